// Round 1
// baseline (490.512 us; speedup 1.0000x reference)
//
#include <hip/hip_runtime.h>
#include <hip/hip_bf16.h>

constexpr int kN = 10000;
constexpr int kE = 25000;
constexpr int kB = 128;
constexpr int kNF = 32;
constexpr int kEF = 8;
constexpr int kD = 64;
constexpr int kEPad = 25088;   // 196 * 128

typedef __attribute__((ext_vector_type(8))) short short8;
typedef __attribute__((ext_vector_type(4))) float floatx4;

__device__ __forceinline__ unsigned short f2bf(float f) {
  unsigned u = __float_as_uint(f);
  u = (u + 0x7fffu + ((u >> 16) & 1u)) >> 16;   // RNE
  return (unsigned short)u;
}
__device__ __forceinline__ float bflo(unsigned u) { return __uint_as_float(u << 16); }
__device__ __forceinline__ float bfhi(unsigned u) { return __uint_as_float(u & 0xffff0000u); }
__device__ __forceinline__ float sigmf(float x) { return 1.f / (1.f + __expf(-x)); }
__device__ __forceinline__ float tanh_(float x) { return 1.f - 2.f / (__expf(2.f * x) + 1.f); }

// ---------------- node dense0: out = relu(x @ W0 + b0) ----------------
__global__ __launch_bounds__(256) void k_dense0(const float* __restrict__ x,
    const float* __restrict__ W0, const float* __restrict__ b0, float* __restrict__ out) {
  int gid = blockIdx.x * 256 + threadIdx.x;          // kN*64 threads exactly
  int n = gid >> 6, f = gid & 63;
  float acc = b0[f];
  const float* xr = x + n * kNF;
#pragma unroll
  for (int j = 0; j < kNF; ++j) acc += xr[j] * W0[j * kD + f];
  out[gid] = fmaxf(acc, 0.f);
}

// ---------------- edge MLP stage 1: hid = relu(ea @ We1 + be1), bf16, XOR-swizzled rows ----
__global__ __launch_bounds__(256) void k_hidden(const float* __restrict__ ea,
    const float* __restrict__ We1, const float* __restrict__ be1,
    unsigned short* __restrict__ hid) {
  int gid = blockIdx.x * 256 + threadIdx.x;          // kE*128 threads exactly
  int e = gid >> 7, k = gid & 127;
  float acc = be1[k];
  const float* er = ea + e * kEF;
#pragma unroll
  for (int j = 0; j < kEF; ++j) acc += er[j] * We1[j * 128 + k];
  acc = fmaxf(acc, 0.f);
  int ks = k ^ ((e & 7) << 3);                       // st-16B swizzle within 256B row
  hid[(size_t)e * 128 + ks] = f2bf(acc);
}

// ---------------- We2 -> bf16, transposed [4096][128], XOR-swizzled rows ----------------
__global__ __launch_bounds__(256) void k_cvt_w(const float* __restrict__ We2,
    unsigned short* __restrict__ w2t) {
  int gid = blockIdx.x * 256 + threadIdx.x;          // 4096*16 threads
  int n = gid >> 4, kg = gid & 15;
  short8 v;
#pragma unroll
  for (int j = 0; j < 8; ++j) v[j] = (short)f2bf(We2[(kg * 8 + j) * 4096 + n]);
  int ks = (kg * 8) ^ ((n & 7) << 3);
  *(short8*)(w2t + (size_t)n * 128 + ks) = v;
}

// ---------------- degree ----------------
__global__ __launch_bounds__(256) void k_deg(const int* __restrict__ ei, float* __restrict__ deg) {
  int e = blockIdx.x * 256 + threadIdx.x;
  if (e < kE) atomicAdd(&deg[ei[kE + e]], 1.f);
}

// ---------------- per-graph node ranges (batch is sorted) ----------------
__global__ void k_bounds(const int* __restrict__ batch, int* __restrict__ start) {
  int t = threadIdx.x;
  if (t > kB) return;
  int lo = 0, hi = kN;
  while (lo < hi) { int mid = (lo + hi) >> 1; if (batch[mid] < t) lo = mid + 1; else hi = mid; }
  start[t] = lo;
}

// ---------------- ew = hid @ We2 + be2  (bf16 MFMA, 128x128 tile, K=128 one-shot) -------
__global__ __launch_bounds__(256) void k_ew_gemm(const unsigned short* __restrict__ hid,
    const unsigned short* __restrict__ w2t, const float* __restrict__ be2,
    unsigned short* __restrict__ ew) {
  __shared__ __align__(16) unsigned short Ash[128 * 128];
  __shared__ __align__(16) unsigned short Bsh[128 * 128];
  int t = threadIdx.x;
  int wave = t >> 6, lane = t & 63;
  int tm = blockIdx.x, tn = blockIdx.y;
  const char* aBase = (const char*)(hid + (size_t)tm * 128 * 128);
  const char* bBase = (const char*)(w2t + (size_t)tn * 128 * 128);
#pragma unroll
  for (int it = 0; it < 8; ++it) {
    int boff = ((it * 4 + wave) << 10) + (lane << 4);
    __builtin_amdgcn_global_load_lds(
        (const __attribute__((address_space(1))) void*)(aBase + boff),
        (__attribute__((address_space(3))) void*)((char*)Ash + boff), 16, 0, 0);
    __builtin_amdgcn_global_load_lds(
        (const __attribute__((address_space(1))) void*)(bBase + boff),
        (__attribute__((address_space(3))) void*)((char*)Bsh + boff), 16, 0, 0);
  }
  __syncthreads();
  int wm = wave >> 1, wn = wave & 1;        // 2x2 waves -> 64x64 quadrant each
  int lrow = lane & 15, kblk = lane >> 4;
  floatx4 acc[4][4];
#pragma unroll
  for (int i = 0; i < 4; ++i)
#pragma unroll
    for (int j = 0; j < 4; ++j) acc[i][j] = (floatx4){0.f, 0.f, 0.f, 0.f};
#pragma unroll
  for (int kk = 0; kk < 4; ++kk) {
    int kelem = kk * 32 + kblk * 8;
    short8 av[4], bv[4];
#pragma unroll
    for (int mf = 0; mf < 4; ++mf) {
      int row = wm * 64 + mf * 16 + lrow;
      int ke = kelem ^ ((row & 7) << 3);
      av[mf] = *(const short8*)&Ash[row * 128 + ke];
    }
#pragma unroll
    for (int nf = 0; nf < 4; ++nf) {
      int row = wn * 64 + nf * 16 + lrow;
      int ke = kelem ^ ((row & 7) << 3);
      bv[nf] = *(const short8*)&Bsh[row * 128 + ke];
    }
#pragma unroll
    for (int mf = 0; mf < 4; ++mf)
#pragma unroll
      for (int nf = 0; nf < 4; ++nf)
        acc[mf][nf] = __builtin_amdgcn_mfma_f32_16x16x32_bf16(av[mf], bv[nf], acc[mf][nf], 0, 0, 0);
  }
  int ccol = lane & 15, rgrp = lane >> 4;   // C/D: col=lane&15, row=(lane>>4)*4+r
#pragma unroll
  for (int nf = 0; nf < 4; ++nf) {
    int gcol = tn * 128 + wn * 64 + nf * 16 + ccol;
    float bias = be2[gcol];
#pragma unroll
    for (int mf = 0; mf < 4; ++mf) {
      int grow = tm * 128 + wm * 64 + mf * 16 + rgrp * 4;
#pragma unroll
      for (int r = 0; r < 4; ++r) {
        int er = grow + r;
        if (er < kE) ew[(size_t)er * 4096 + gcol] = f2bf(acc[mf][nf][r] + bias);
      }
    }
  }
}

// ---------------- per-edge message: msg[e] = out[src] @ ew[e]; atomic agg[dst] ------------
__global__ __launch_bounds__(256) void k_msg(const int* __restrict__ ei,
    const unsigned short* __restrict__ ew, const float* __restrict__ out,
    float* __restrict__ agg) {
  int wid = (blockIdx.x * 256 + threadIdx.x) >> 6;   // one wave per edge
  int lane = threadIdx.x & 63;
  if (wid >= kE) return;
  int src = ei[wid];
  int dst = ei[kE + wid];
  float o = out[src * kD + lane];
  float acc[8] = {0, 0, 0, 0, 0, 0, 0, 0};
  const unsigned short* ewp = ew + (size_t)wid * 4096;
  int dbase = lane >> 3, f0 = (lane & 7) << 3;
#pragma unroll
  for (int dc = 0; dc < 8; ++dc) {
    int d = dc * 8 + dbase;
    uint4 wv = *(const uint4*)(ewp + d * 64 + f0);   // contiguous 1KB per wave per iter
    float ov = __shfl(o, d, 64);
    acc[0] += ov * bflo(wv.x); acc[1] += ov * bfhi(wv.x);
    acc[2] += ov * bflo(wv.y); acc[3] += ov * bfhi(wv.y);
    acc[4] += ov * bflo(wv.z); acc[5] += ov * bfhi(wv.z);
    acc[6] += ov * bflo(wv.w); acc[7] += ov * bfhi(wv.w);
  }
#pragma unroll
  for (int m = 8; m <= 32; m <<= 1) {
#pragma unroll
    for (int j = 0; j < 8; ++j) acc[j] += __shfl_xor(acc[j], m, 64);
  }
  if (lane < 8) {
    float* ap = agg + (size_t)dst * kD + lane * 8;
#pragma unroll
    for (int j = 0; j < 8; ++j) atomicAdd(ap + j, acc[j]);
  }
}

// ---------------- fused NNConv-combine + GRU cell (16 nodes / block) ----------------
__global__ __launch_bounds__(256) void k_update(const float* __restrict__ agg,
    const float* __restrict__ deg, const float* __restrict__ root,
    const float* __restrict__ convb, const float* __restrict__ Wi,
    const float* __restrict__ bi, const float* __restrict__ Wh,
    const float* __restrict__ bh, float* __restrict__ out) {
  __shared__ float sh_out[16][64];
  __shared__ float sh_m[16][64];
  int t = threadIdx.x, lane = t & 63, w = t >> 6;
  int nb = blockIdx.x * 16;
#pragma unroll
  for (int i = 0; i < 4; ++i) {
    int idx = t + i * 256;
    sh_out[idx >> 6][idx & 63] = out[(size_t)(nb + (idx >> 6)) * 64 + (idx & 63)];
  }
  __syncthreads();
  int n0 = w * 4;
  float acc[4];
#pragma unroll
  for (int i = 0; i < 4; ++i) {
    int n = nb + n0 + i;
    float dg = fmaxf(deg[n], 1.f);
    acc[i] = agg[(size_t)n * 64 + lane] / dg + convb[lane];
  }
  for (int d = 0; d < 64; ++d) {
    float rv = root[d * 64 + lane];
#pragma unroll
    for (int i = 0; i < 4; ++i) acc[i] += sh_out[n0 + i][d] * rv;
  }
#pragma unroll
  for (int i = 0; i < 4; ++i) sh_m[n0 + i][lane] = fmaxf(acc[i], 0.f);
  __syncthreads();
  float ir[4] = {}, iz[4] = {}, ig[4] = {}, hr[4] = {}, hz[4] = {}, hg[4] = {};
  for (int d = 0; d < 64; ++d) {
    float wi0 = Wi[d * 192 + lane], wi1 = Wi[d * 192 + 64 + lane], wi2 = Wi[d * 192 + 128 + lane];
    float wh0 = Wh[d * 192 + lane], wh1 = Wh[d * 192 + 64 + lane], wh2 = Wh[d * 192 + 128 + lane];
#pragma unroll
    for (int i = 0; i < 4; ++i) {
      float mv = sh_m[n0 + i][d], hv = sh_out[n0 + i][d];
      ir[i] += mv * wi0; iz[i] += mv * wi1; ig[i] += mv * wi2;
      hr[i] += hv * wh0; hz[i] += hv * wh1; hg[i] += hv * wh2;
    }
  }
  float bi0 = bi[lane], bi1 = bi[64 + lane], bi2 = bi[128 + lane];
  float bh0 = bh[lane], bh1 = bh[64 + lane], bh2 = bh[128 + lane];
#pragma unroll
  for (int i = 0; i < 4; ++i) {
    float r = sigmf(ir[i] + bi0 + hr[i] + bh0);
    float z = sigmf(iz[i] + bi1 + hz[i] + bh1);
    float nn = tanh_(ig[i] + bi2 + r * (hg[i] + bh2));
    float h = sh_out[n0 + i][lane];
    out[(size_t)(nb + n0 + i) * 64 + lane] = (1.f - z) * nn + z * h;
  }
}

// ---------------- one full Set2Set step: LSTM + attention readout (block = graph) --------
__global__ __launch_bounds__(256) void k_s2s(const float* __restrict__ out,
    const int* __restrict__ start, const float* __restrict__ Wli,
    const float* __restrict__ bli, const float* __restrict__ Wlh,
    const float* __restrict__ blh, float* __restrict__ q_star,
    float* __restrict__ hl, float* __restrict__ cl) {
  __shared__ float qs[128], hls[64], cls[64], gates[256];
  __shared__ float ebuf[1024];
  __shared__ float part[4][64];
  __shared__ float sred[8];
  int b = blockIdx.x, t = threadIdx.x, lane = t & 63, w = t >> 6;
  if (t < 128) qs[t] = q_star[b * 128 + t];
  if (t < 64) { hls[t] = hl[b * 64 + t]; cls[t] = cl[b * 64 + t]; }
  __syncthreads();
  float g = bli[t] + blh[t];
  for (int j = 0; j < 128; ++j) g += qs[j] * Wli[j * 256 + t];
  for (int j = 0; j < 64; ++j) g += hls[j] * Wlh[j * 256 + t];
  gates[t] = g;
  __syncthreads();
  if (t < 64) {                      // gate order i, f, g, o
    float ig = sigmf(gates[t]), fg = sigmf(gates[64 + t]);
    float gg = tanh_(gates[128 + t]), og = sigmf(gates[192 + t]);
    float c = fg * cls[t] + ig * gg;
    float h = og * tanh_(c);
    cls[t] = c; hls[t] = h;
    cl[b * 64 + t] = c; hl[b * 64 + t] = h;
    q_star[b * 128 + t] = h;         // q part of q_star
  }
  __syncthreads();
  int s0 = start[b], s1 = start[b + 1];
  int cnt = s1 - s0; if (cnt > 1024) cnt = 1024;
  for (int idx = w; idx < cnt; idx += 4) {            // e[n] = <out[n], q>
    int node = s0 + idx;
    float p = out[(size_t)node * 64 + lane] * hls[lane];
#pragma unroll
    for (int m = 1; m < 64; m <<= 1) p += __shfl_xor(p, m, 64);
    if (lane == 0) ebuf[idx] = p;
  }
  __syncthreads();
  float mx = -3.4e38f;
  for (int idx = t; idx < cnt; idx += 256) mx = fmaxf(mx, ebuf[idx]);
#pragma unroll
  for (int m = 1; m < 64; m <<= 1) mx = fmaxf(mx, __shfl_xor(mx, m, 64));
  if (lane == 0) sred[w] = mx;
  __syncthreads();
  mx = fmaxf(fmaxf(sred[0], sred[1]), fmaxf(sred[2], sred[3]));
  float s = 0.f;
  for (int idx = t; idx < cnt; idx += 256) {
    float a = __expf(ebuf[idx] - mx);
    ebuf[idx] = a; s += a;
  }
#pragma unroll
  for (int m = 1; m < 64; m <<= 1) s += __shfl_xor(s, m, 64);
  if (lane == 0) sred[4 + w] = s;
  __syncthreads();
  s = sred[4] + sred[5] + sred[6] + sred[7];
  float rs = 1.f / fmaxf(s, 1e-12f);
  float pr = 0.f;
  for (int idx = w; idx < cnt; idx += 4) {
    int node = s0 + idx;
    pr += ebuf[idx] * out[(size_t)node * 64 + lane];
  }
  part[w][lane] = pr;
  __syncthreads();
  if (t < 64)
    q_star[b * 128 + 64 + t] = (part[0][t] + part[1][t] + part[2][t] + part[3][t]) * rs;
}

// ---------------- head: y1 = q_star @ Wr1 + br1 ----------------
__global__ __launch_bounds__(64) void k_head1(const float* __restrict__ q_star,
    const float* __restrict__ Wr1, const float* __restrict__ br1, float* __restrict__ y1) {
  int b = blockIdx.x, f = threadIdx.x;
  float acc = br1[f];
  const float* q = q_star + b * 128;
  for (int j = 0; j < 128; ++j) acc += q[j] * Wr1[j * 64 + f];
  y1[b * 64 + f] = acc;
}

// ---------------- head: BatchNorm (batch stats) + relu + Wr2 ----------------
__global__ __launch_bounds__(256) void k_head2(const float* __restrict__ y1,
    const float* __restrict__ gamma, const float* __restrict__ beta,
    const float* __restrict__ Wr2, const float* __restrict__ br2,
    float* __restrict__ outp) {
  __shared__ float mu[64], ri[64];
  int t = threadIdx.x;
  if (t < 64) {
    float s1 = 0.f, s2 = 0.f;
    for (int b = 0; b < kB; ++b) { float v = y1[b * 64 + t]; s1 += v; s2 += v * v; }
    float m = s1 / (float)kB;
    mu[t] = m; ri[t] = rsqrtf(s2 / (float)kB - m * m + 1e-5f);
  }
  __syncthreads();
  if (t < kB) {
    float acc = br2[0];
    for (int f = 0; f < 64; ++f) {
      float v = (y1[t * 64 + f] - mu[f]) * ri[f] * gamma[f] + beta[f];
      acc += fmaxf(v, 0.f) * Wr2[f];
    }
    outp[t] = acc;
  }
}

extern "C" void kernel_launch(void* const* d_in, const int* in_sizes, int n_in,
                              void* d_out, int out_size, void* d_ws, size_t ws_size,
                              hipStream_t stream) {
  const float* x     = (const float*)d_in[0];
  const int*   ei    = (const int*)d_in[1];
  const float* ea    = (const float*)d_in[2];
  const int*   batch = (const int*)d_in[3];
  const float* W0    = (const float*)d_in[4];
  const float* b0    = (const float*)d_in[5];
  const float* We1   = (const float*)d_in[6];
  const float* be1   = (const float*)d_in[7];
  const float* We2   = (const float*)d_in[8];
  const float* be2   = (const float*)d_in[9];
  const float* root  = (const float*)d_in[10];
  const float* convb = (const float*)d_in[11];
  const float* Wi    = (const float*)d_in[12];
  const float* bi    = (const float*)d_in[13];
  const float* Wh    = (const float*)d_in[14];
  const float* bh    = (const float*)d_in[15];
  const float* Wli   = (const float*)d_in[16];
  const float* bli   = (const float*)d_in[17];
  const float* Wlh   = (const float*)d_in[18];
  const float* blh   = (const float*)d_in[19];
  const float* Wr1   = (const float*)d_in[20];
  const float* br1   = (const float*)d_in[21];
  const float* gamma = (const float*)d_in[22];
  const float* beta  = (const float*)d_in[23];
  const float* Wr2   = (const float*)d_in[24];
  const float* br2   = (const float*)d_in[25];
  (void)in_sizes; (void)n_in; (void)out_size; (void)ws_size;

  char* ws = (char*)d_ws;
  size_t off = 0;
  auto take = [&](size_t bytes) {
    char* p = ws + off;
    off += (bytes + 255) & ~(size_t)255;
    return p;
  };
  unsigned short* ew  = (unsigned short*)take((size_t)kE * 4096 * 2);    // 204.8 MB
  unsigned short* hid = (unsigned short*)take((size_t)kEPad * 128 * 2);  // 6.4 MB
  unsigned short* w2t = (unsigned short*)take((size_t)4096 * 128 * 2);   // 1 MB
  float* outn  = (float*)take((size_t)kN * kD * 4);
  float* agg   = (float*)take((size_t)kN * kD * 4);
  float* deg   = (float*)take((size_t)kN * 4);
  int*   start = (int*)take(256 * 4);
  float* qstar = (float*)take((size_t)kB * 128 * 4);   // qstar, hl, cl contiguous
  float* hl    = (float*)take((size_t)kB * 64 * 4);
  float* cl    = (float*)take((size_t)kB * 64 * 4);
  float* y1    = (float*)take((size_t)kB * 64 * 4);

  hipMemsetAsync(deg, 0, (size_t)kN * 4, stream);
  hipMemsetAsync(qstar, 0, (size_t)(kB * 128 + kB * 64 + kB * 64) * 4, stream);

  k_dense0<<<kN * kD / 256, 256, 0, stream>>>(x, W0, b0, outn);
  k_hidden<<<kE * 128 / 256, 256, 0, stream>>>(ea, We1, be1, hid);
  k_cvt_w<<<4096 * 16 / 256, 256, 0, stream>>>(We2, w2t);
  k_deg<<<(kE + 255) / 256, 256, 0, stream>>>(ei, deg);
  k_bounds<<<1, 256, 0, stream>>>(batch, start);
  dim3 gg(kEPad / 128, 4096 / 128);
  k_ew_gemm<<<gg, 256, 0, stream>>>(hid, w2t, be2, ew);

  for (int s = 0; s < 3; ++s) {
    hipMemsetAsync(agg, 0, (size_t)kN * kD * 4, stream);
    k_msg<<<(kE * 64 + 255) / 256, 256, 0, stream>>>(ei, ew, outn, agg);
    k_update<<<kN / 16, 256, 0, stream>>>(agg, deg, root, convb, Wi, bi, Wh, bh, outn);
  }
  for (int s = 0; s < 3; ++s)
    k_s2s<<<kB, 256, 0, stream>>>(outn, start, Wli, bli, Wlh, blh, qstar, hl, cl);

  k_head1<<<kB, 64, 0, stream>>>(qstar, Wr1, br1, y1);
  k_head2<<<1, 256, 0, stream>>>(y1, gamma, beta, Wr2, br2, (float*)d_out);
}

// Round 2
// 376.700 us; speedup vs baseline: 1.3021x; 1.3021x over previous
//
#include <hip/hip_runtime.h>
#include <hip/hip_bf16.h>

constexpr int kN = 10000;
constexpr int kE = 25000;
constexpr int kB = 128;
constexpr int kNF = 32;
constexpr int kEF = 8;
constexpr int kD = 64;
constexpr int kEPadT = 25088;     // hidT column padding (392*64)
constexpr int kChunks = 65;       // 64 full (K=8192) + 1 bias chunk (K=64 valid)

typedef __attribute__((ext_vector_type(8))) short short8;
typedef __attribute__((ext_vector_type(4))) float floatx4;

__device__ __forceinline__ unsigned short f2bf(float f) {
  unsigned u = __float_as_uint(f);
  u = (u + 0x7fffu + ((u >> 16) & 1u)) >> 16;   // RNE
  return (unsigned short)u;
}
__device__ __forceinline__ float bf2f(unsigned short s) {
  return __uint_as_float(((unsigned)s) << 16);
}
__device__ __forceinline__ float sigmf(float x) { return 1.f / (1.f + __expf(-x)); }
__device__ __forceinline__ float tanh_(float x) { return 1.f - 2.f / (__expf(2.f * x) + 1.f); }

__device__ __forceinline__ unsigned cvtpk(float lo, float hi) {
  unsigned r;
  asm("v_cvt_pk_bf16_f32 %0, %1, %2" : "=v"(r) : "v"(lo), "v"(hi));
  return r;
}

// ---------------- node dense0: out = relu(x @ W0 + b0) ----------------
__global__ __launch_bounds__(256) void k_dense0(const float* __restrict__ x,
    const float* __restrict__ W0, const float* __restrict__ b0, float* __restrict__ out) {
  int gid = blockIdx.x * 256 + threadIdx.x;          // kN*64 threads exactly
  int n = gid >> 6, f = gid & 63;
  float acc = b0[f];
  const float* xr = x + n * kNF;
#pragma unroll
  for (int j = 0; j < kNF; ++j) acc += xr[j] * W0[j * kD + f];
  out[gid] = fmaxf(acc, 0.f);
}

// ---------------- edge MLP stage 1, TRANSPOSED: hidT[h][e] = bf16(relu(ea@We1+be1)) ------
__global__ __launch_bounds__(256) void k_hidden(const float* __restrict__ ea,
    const float* __restrict__ We1, const float* __restrict__ be1,
    unsigned short* __restrict__ hidT) {
  int e = blockIdx.x * 256 + threadIdx.x;            // grid (98, 128)
  int h = blockIdx.y;
  if (e >= kEPadT) return;
  float acc = 0.f;
  if (e < kE) {
    acc = be1[h];
    const float* er = ea + e * kEF;
#pragma unroll
    for (int j = 0; j < kEF; ++j) acc += er[j] * We1[j * 128 + h];
    acc = fmaxf(acc, 0.f);
  }
  hidT[(size_t)h * kEPadT + e] = f2bf(acc);
}

// ---------------- B precompute: fragment-major Bc[c][ks][nf][lane][8] bf16 ----------------
// k = c*128 + ks*32 + (lane>>4)*8 + j ; f = nf*16 + (lane&15)
// k < 8192: B = We2[k>>6, (k&63)*64 + f]; 8192<=k<8256: B = be2[(k-8192)*64+f]; else 0
__global__ __launch_bounds__(256) void k_prep_b(const float* __restrict__ We2,
    const float* __restrict__ be2, unsigned short* __restrict__ Bc) {
  int gid = blockIdx.x * 256 + threadIdx.x;          // 65*4*4*64 = 66560 = 260*256
  int l = gid & 63, nf = (gid >> 6) & 3, ks = (gid >> 8) & 3, c = gid >> 10;
  int f = nf * 16 + (l & 15);
  int kbase = c * 128 + ks * 32 + (l >> 4) * 8;
  unsigned short v[8];
#pragma unroll
  for (int j = 0; j < 8; ++j) {
    int k = kbase + j;
    float x = 0.f;
    if (k < 8192) x = We2[(size_t)(k >> 6) * 4096 + (k & 63) * 64 + f];
    else if (k < 8256) x = be2[(k - 8192) * 64 + f];
    v[j] = f2bf(x);
  }
  *(short8*)(Bc + (size_t)gid * 8) = *(short8*)v;
}

// ---------------- degree ----------------
__global__ __launch_bounds__(256) void k_deg(const int* __restrict__ ei, float* __restrict__ deg) {
  int e = blockIdx.x * 256 + threadIdx.x;
  if (e < kE) atomicAdd(&deg[ei[kE + e]], 1.f);
}

// ---------------- per-graph node ranges (batch is sorted) ----------------
__global__ void k_bounds(const int* __restrict__ batch, int* __restrict__ start) {
  int t = threadIdx.x;
  if (t > kB) return;
  int lo = 0, hi = kN;
  while (lo < hi) { int mid = (lo + hi) >> 1; if (batch[mid] < t) lo = mid + 1; else hi = mid; }
  start[t] = lo;
}

// ---------------- fused message GEMM: agg[dst] += out[src] @ (reshape(hid@We2+be2)) ------
// Block = 64 edges, 256 thr = 4 waves; wave: M=64, N=16 (wn = wave id).
// A[e, k=(h,d)] = hid[e,h]*out[src(e),d]  built in registers (out lives in VGPRs:
// per lane only d-octets {kblk*8, kblk*8+32} ever appear). B read fragment-major
// direct from global (L1/L2-hot). No barriers in K-loop.
__global__ __launch_bounds__(256) void k_msg_fused(const int* __restrict__ ei,
    const float* __restrict__ outn, const unsigned short* __restrict__ hidT,
    const unsigned short* __restrict__ Bc, float* __restrict__ agg) {
  __shared__ __align__(16) unsigned short hidS[128 * 64];   // [h][e_loc], 128B rows, 16KB
  const int t = threadIdx.x, lane = t & 63, wn = t >> 6;
  const int e0 = blockIdx.x * 64;
  // stage hidT tile (rows h=0..127, cols e0..e0+63): 16 x 1KB, 4 instrs/wave,
  // per-lane global src (8 rows x 128B per instr), linear LDS dest.
#pragma unroll
  for (int i = 0; i < 4; ++i) {
    int inst = wn * 4 + i;
    int row = inst * 8 + (lane >> 3);
    const unsigned short* src = hidT + (size_t)row * kEPadT + e0 + (lane & 7) * 8;
    __builtin_amdgcn_global_load_lds(
        (const __attribute__((address_space(1))) void*)src,
        (__attribute__((address_space(3))) void*)((char*)hidS + inst * 1024 + lane * 16),
        16, 0, 0);
  }
  // gather out[src] rows into registers: 4 m-fragments x 2 d-octets x 8 floats
  const int lrow = lane & 15, kblk = lane >> 4;
  float4 o[4][4];          // [mf][dc*2+half]
#pragma unroll
  for (int mf = 0; mf < 4; ++mf) {
    int e = e0 + mf * 16 + lrow;
    int s = (e < kE) ? ei[e] : 0;
    const float* orow = outn + (size_t)s * 64 + kblk * 8;
    o[mf][0] = *(const float4*)(orow);
    o[mf][1] = *(const float4*)(orow + 4);
    o[mf][2] = *(const float4*)(orow + 32);
    o[mf][3] = *(const float4*)(orow + 36);
  }
  __syncthreads();   // hidS ready

  floatx4 acc[4];
#pragma unroll
  for (int mf = 0; mf < 4; ++mf) acc[mf] = (floatx4){0.f, 0.f, 0.f, 0.f};

  for (int c = 0; c < 64; ++c) {
    float hv[4][2];
#pragma unroll
    for (int mf = 0; mf < 4; ++mf) {
      int eloc = mf * 16 + lrow;
      hv[mf][0] = bf2f(hidS[(2 * c) * 64 + eloc]);
      hv[mf][1] = bf2f(hidS[(2 * c + 1) * 64 + eloc]);
    }
#pragma unroll
    for (int ks = 0; ks < 4; ++ks) {
      short8 bv = *(const short8*)(Bc + ((((size_t)c * 4 + ks) * 4 + wn) * 64 + lane) * 8);
      const int hh = ks >> 1, dc = ks & 1;
#pragma unroll
      for (int mf = 0; mf < 4; ++mf) {
        float h = hv[mf][hh];
        float4 va = o[mf][dc * 2], vb = o[mf][dc * 2 + 1];
        union { uint4 u; short8 s; } U;
        U.u.x = cvtpk(va.x * h, va.y * h);
        U.u.y = cvtpk(va.z * h, va.w * h);
        U.u.z = cvtpk(vb.x * h, vb.y * h);
        U.u.w = cvtpk(vb.z * h, vb.w * h);
        acc[mf] = __builtin_amdgcn_mfma_f32_16x16x32_bf16(U.s, bv, acc[mf], 0, 0, 0);
      }
    }
  }
  // bias chunk (c=64): ks 0,1 only; A = bf16(out) directly (weight 1)
#pragma unroll
  for (int ks = 0; ks < 2; ++ks) {
    short8 bv = *(const short8*)(Bc + ((((size_t)64 * 4 + ks) * 4 + wn) * 64 + lane) * 8);
#pragma unroll
    for (int mf = 0; mf < 4; ++mf) {
      float4 va = o[mf][ks * 2], vb = o[mf][ks * 2 + 1];
      union { uint4 u; short8 s; } U;
      U.u.x = cvtpk(va.x, va.y);
      U.u.y = cvtpk(va.z, va.w);
      U.u.z = cvtpk(vb.x, vb.y);
      U.u.w = cvtpk(vb.z, vb.w);
      acc[mf] = __builtin_amdgcn_mfma_f32_16x16x32_bf16(U.s, bv, acc[mf], 0, 0, 0);
    }
  }
  // epilogue: atomic scatter into agg[dst]
  const int ccol = lane & 15, rg = lane >> 4;
  const int f = wn * 16 + ccol;
#pragma unroll
  for (int mf = 0; mf < 4; ++mf) {
#pragma unroll
    for (int r = 0; r < 4; ++r) {
      int e = e0 + mf * 16 + rg * 4 + r;
      if (e < kE) {
        int dst = ei[kE + e];
        atomicAdd(agg + (size_t)dst * 64 + f, acc[mf][r]);
      }
    }
  }
}

// ---------------- fused NNConv-combine + GRU cell (16 nodes / block) ----------------
__global__ __launch_bounds__(256) void k_update(const float* __restrict__ agg,
    const float* __restrict__ deg, const float* __restrict__ root,
    const float* __restrict__ convb, const float* __restrict__ Wi,
    const float* __restrict__ bi, const float* __restrict__ Wh,
    const float* __restrict__ bh, float* __restrict__ out) {
  __shared__ float sh_out[16][64];
  __shared__ float sh_m[16][64];
  int t = threadIdx.x, lane = t & 63, w = t >> 6;
  int nb = blockIdx.x * 16;
#pragma unroll
  for (int i = 0; i < 4; ++i) {
    int idx = t + i * 256;
    sh_out[idx >> 6][idx & 63] = out[(size_t)(nb + (idx >> 6)) * 64 + (idx & 63)];
  }
  __syncthreads();
  int n0 = w * 4;
  float acc[4];
#pragma unroll
  for (int i = 0; i < 4; ++i) {
    int n = nb + n0 + i;
    float dg = fmaxf(deg[n], 1.f);
    acc[i] = agg[(size_t)n * 64 + lane] / dg + convb[lane];
  }
  for (int d = 0; d < 64; ++d) {
    float rv = root[d * 64 + lane];
#pragma unroll
    for (int i = 0; i < 4; ++i) acc[i] += sh_out[n0 + i][d] * rv;
  }
#pragma unroll
  for (int i = 0; i < 4; ++i) sh_m[n0 + i][lane] = fmaxf(acc[i], 0.f);
  __syncthreads();
  float ir[4] = {}, iz[4] = {}, ig[4] = {}, hr[4] = {}, hz[4] = {}, hg[4] = {};
  for (int d = 0; d < 64; ++d) {
    float wi0 = Wi[d * 192 + lane], wi1 = Wi[d * 192 + 64 + lane], wi2 = Wi[d * 192 + 128 + lane];
    float wh0 = Wh[d * 192 + lane], wh1 = Wh[d * 192 + 64 + lane], wh2 = Wh[d * 192 + 128 + lane];
#pragma unroll
    for (int i = 0; i < 4; ++i) {
      float mv = sh_m[n0 + i][d], hv = sh_out[n0 + i][d];
      ir[i] += mv * wi0; iz[i] += mv * wi1; ig[i] += mv * wi2;
      hr[i] += hv * wh0; hz[i] += hv * wh1; hg[i] += hv * wh2;
    }
  }
  float bi0 = bi[lane], bi1 = bi[64 + lane], bi2 = bi[128 + lane];
  float bh0 = bh[lane], bh1 = bh[64 + lane], bh2 = bh[128 + lane];
#pragma unroll
  for (int i = 0; i < 4; ++i) {
    float r = sigmf(ir[i] + bi0 + hr[i] + bh0);
    float z = sigmf(iz[i] + bi1 + hz[i] + bh1);
    float nn = tanh_(ig[i] + bi2 + r * (hg[i] + bh2));
    float h = sh_out[n0 + i][lane];
    out[(size_t)(nb + n0 + i) * 64 + lane] = (1.f - z) * nn + z * h;
  }
}

// ---------------- one full Set2Set step: LSTM + attention readout (block = graph) --------
__global__ __launch_bounds__(256) void k_s2s(const float* __restrict__ out,
    const int* __restrict__ start, const float* __restrict__ Wli,
    const float* __restrict__ bli, const float* __restrict__ Wlh,
    const float* __restrict__ blh, float* __restrict__ q_star,
    float* __restrict__ hl, float* __restrict__ cl) {
  __shared__ float qs[128], hls[64], cls[64], gates[256];
  __shared__ float ebuf[1024];
  __shared__ float part[4][64];
  __shared__ float sred[8];
  int b = blockIdx.x, t = threadIdx.x, lane = t & 63, w = t >> 6;
  if (t < 128) qs[t] = q_star[b * 128 + t];
  if (t < 64) { hls[t] = hl[b * 64 + t]; cls[t] = cl[b * 64 + t]; }
  __syncthreads();
  float g = bli[t] + blh[t];
  for (int j = 0; j < 128; ++j) g += qs[j] * Wli[j * 256 + t];
  for (int j = 0; j < 64; ++j) g += hls[j] * Wlh[j * 256 + t];
  gates[t] = g;
  __syncthreads();
  if (t < 64) {                      // gate order i, f, g, o
    float ig = sigmf(gates[t]), fg = sigmf(gates[64 + t]);
    float gg = tanh_(gates[128 + t]), og = sigmf(gates[192 + t]);
    float c = fg * cls[t] + ig * gg;
    float h = og * tanh_(c);
    cls[t] = c; hls[t] = h;
    cl[b * 64 + t] = c; hl[b * 64 + t] = h;
    q_star[b * 128 + t] = h;         // q part of q_star
  }
  __syncthreads();
  int s0 = start[b], s1 = start[b + 1];
  int cnt = s1 - s0; if (cnt > 1024) cnt = 1024;
  for (int idx = w; idx < cnt; idx += 4) {            // e[n] = <out[n], q>
    int node = s0 + idx;
    float p = out[(size_t)node * 64 + lane] * hls[lane];
#pragma unroll
    for (int m = 1; m < 64; m <<= 1) p += __shfl_xor(p, m, 64);
    if (lane == 0) ebuf[idx] = p;
  }
  __syncthreads();
  float mx = -3.4e38f;
  for (int idx = t; idx < cnt; idx += 256) mx = fmaxf(mx, ebuf[idx]);
#pragma unroll
  for (int m = 1; m < 64; m <<= 1) mx = fmaxf(mx, __shfl_xor(mx, m, 64));
  if (lane == 0) sred[w] = mx;
  __syncthreads();
  mx = fmaxf(fmaxf(sred[0], sred[1]), fmaxf(sred[2], sred[3]));
  float s = 0.f;
  for (int idx = t; idx < cnt; idx += 256) {
    float a = __expf(ebuf[idx] - mx);
    ebuf[idx] = a; s += a;
  }
#pragma unroll
  for (int m = 1; m < 64; m <<= 1) s += __shfl_xor(s, m, 64);
  if (lane == 0) sred[4 + w] = s;
  __syncthreads();
  s = sred[4] + sred[5] + sred[6] + sred[7];
  float rs = 1.f / fmaxf(s, 1e-12f);
  float pr = 0.f;
  for (int idx = w; idx < cnt; idx += 4) {
    int node = s0 + idx;
    pr += ebuf[idx] * out[(size_t)node * 64 + lane];
  }
  part[w][lane] = pr;
  __syncthreads();
  if (t < 64)
    q_star[b * 128 + 64 + t] = (part[0][t] + part[1][t] + part[2][t] + part[3][t]) * rs;
}

// ---------------- head: y1 = q_star @ Wr1 + br1 ----------------
__global__ __launch_bounds__(64) void k_head1(const float* __restrict__ q_star,
    const float* __restrict__ Wr1, const float* __restrict__ br1, float* __restrict__ y1) {
  int b = blockIdx.x, f = threadIdx.x;
  float acc = br1[f];
  const float* q = q_star + b * 128;
  for (int j = 0; j < 128; ++j) acc += q[j] * Wr1[j * 64 + f];
  y1[b * 64 + f] = acc;
}

// ---------------- head: BatchNorm (batch stats) + relu + Wr2 ----------------
__global__ __launch_bounds__(256) void k_head2(const float* __restrict__ y1,
    const float* __restrict__ gamma, const float* __restrict__ beta,
    const float* __restrict__ Wr2, const float* __restrict__ br2,
    float* __restrict__ outp) {
  __shared__ float mu[64], ri[64];
  int t = threadIdx.x;
  if (t < 64) {
    float s1 = 0.f, s2 = 0.f;
    for (int b = 0; b < kB; ++b) { float v = y1[b * 64 + t]; s1 += v; s2 += v * v; }
    float m = s1 / (float)kB;
    mu[t] = m; ri[t] = rsqrtf(s2 / (float)kB - m * m + 1e-5f);
  }
  __syncthreads();
  if (t < kB) {
    float acc = br2[0];
    for (int f = 0; f < 64; ++f) {
      float v = (y1[t * 64 + f] - mu[f]) * ri[f] * gamma[f] + beta[f];
      acc += fmaxf(v, 0.f) * Wr2[f];
    }
    outp[t] = acc;
  }
}

extern "C" void kernel_launch(void* const* d_in, const int* in_sizes, int n_in,
                              void* d_out, int out_size, void* d_ws, size_t ws_size,
                              hipStream_t stream) {
  const float* x     = (const float*)d_in[0];
  const int*   ei    = (const int*)d_in[1];
  const float* ea    = (const float*)d_in[2];
  const int*   batch = (const int*)d_in[3];
  const float* W0    = (const float*)d_in[4];
  const float* b0    = (const float*)d_in[5];
  const float* We1   = (const float*)d_in[6];
  const float* be1   = (const float*)d_in[7];
  const float* We2   = (const float*)d_in[8];
  const float* be2   = (const float*)d_in[9];
  const float* root  = (const float*)d_in[10];
  const float* convb = (const float*)d_in[11];
  const float* Wi    = (const float*)d_in[12];
  const float* bi    = (const float*)d_in[13];
  const float* Wh    = (const float*)d_in[14];
  const float* bh    = (const float*)d_in[15];
  const float* Wli   = (const float*)d_in[16];
  const float* bli   = (const float*)d_in[17];
  const float* Wlh   = (const float*)d_in[18];
  const float* blh   = (const float*)d_in[19];
  const float* Wr1   = (const float*)d_in[20];
  const float* br1   = (const float*)d_in[21];
  const float* gamma = (const float*)d_in[22];
  const float* beta  = (const float*)d_in[23];
  const float* Wr2   = (const float*)d_in[24];
  const float* br2   = (const float*)d_in[25];
  (void)in_sizes; (void)n_in; (void)out_size; (void)ws_size;

  char* ws = (char*)d_ws;
  size_t off = 0;
  auto take = [&](size_t bytes) {
    char* p = ws + off;
    off += (bytes + 255) & ~(size_t)255;
    return p;
  };
  unsigned short* hidT = (unsigned short*)take((size_t)128 * kEPadT * 2);   // 6.4 MB
  unsigned short* Bc   = (unsigned short*)take((size_t)kChunks * 8192 * 2); // 1.07 MB
  float* outn  = (float*)take((size_t)kN * kD * 4);
  float* agg   = (float*)take((size_t)kN * kD * 4);
  float* deg   = (float*)take((size_t)kN * 4);
  int*   start = (int*)take(256 * 4);
  float* qstar = (float*)take((size_t)kB * 128 * 4);   // qstar, hl, cl contiguous
  float* hl    = (float*)take((size_t)kB * 64 * 4);
  float* cl    = (float*)take((size_t)kB * 64 * 4);
  float* y1    = (float*)take((size_t)kB * 64 * 4);

  hipMemsetAsync(deg, 0, (size_t)kN * 4, stream);
  hipMemsetAsync(qstar, 0, (size_t)(kB * 128 + kB * 64 + kB * 64) * 4, stream);

  k_dense0<<<kN * kD / 256, 256, 0, stream>>>(x, W0, b0, outn);
  dim3 gh(kEPadT / 256, 128);
  k_hidden<<<gh, 256, 0, stream>>>(ea, We1, be1, hidT);
  k_prep_b<<<kChunks * 4, 256, 0, stream>>>(We2, be2, Bc);   // 65*1024/256 = 260
  k_deg<<<(kE + 255) / 256, 256, 0, stream>>>(ei, deg);
  k_bounds<<<1, 256, 0, stream>>>(batch, start);

  const int nMsgBlocks = (kE + 63) / 64;   // 391
  for (int s = 0; s < 3; ++s) {
    hipMemsetAsync(agg, 0, (size_t)kN * kD * 4, stream);
    k_msg_fused<<<nMsgBlocks, 256, 0, stream>>>(ei, outn, hidT, Bc, agg);
    k_update<<<kN / 16, 256, 0, stream>>>(agg, deg, root, convb, Wi, bi, Wh, bh, outn);
  }
  for (int s = 0; s < 3; ++s)
    k_s2s<<<kB, 256, 0, stream>>>(outn, start, Wli, bli, Wlh, blh, qstar, hl, cl);

  k_head1<<<kB, 64, 0, stream>>>(qstar, Wr1, br1, y1);
  k_head2<<<1, 256, 0, stream>>>(y1, gamma, beta, Wr2, br2, (float*)d_out);
}

// Round 3
// 376.620 us; speedup vs baseline: 1.3024x; 1.0002x over previous
//
#include <hip/hip_runtime.h>
#include <hip/hip_bf16.h>

constexpr int kN = 10000;
constexpr int kE = 25000;
constexpr int kB = 128;
constexpr int kNF = 32;
constexpr int kEF = 8;
constexpr int kD = 64;
constexpr int kEPad = 25088;   // 196 * 128

typedef __attribute__((ext_vector_type(8))) short short8;
typedef __attribute__((ext_vector_type(4))) float floatx4;
typedef __attribute__((ext_vector_type(16))) float floatx16;

__device__ __forceinline__ unsigned short f2bf(float f) {
  unsigned u = __float_as_uint(f);
  u = (u + 0x7fffu + ((u >> 16) & 1u)) >> 16;   // RNE
  return (unsigned short)u;
}
__device__ __forceinline__ float sigmf(float x) { return 1.f / (1.f + __expf(-x)); }
__device__ __forceinline__ float tanh_(float x) { return 1.f - 2.f / (__expf(2.f * x) + 1.f); }

__device__ __forceinline__ unsigned cvtpk(float lo, float hi) {
  unsigned r;
  asm("v_cvt_pk_bf16_f32 %0, %1, %2" : "=v"(r) : "v"(lo), "v"(hi));
  return r;
}

// ============ fused setup: dense0 | hidden(e-major) | prep_b | deg | bounds ============
constexpr int kBlkDense = 2500;                 // kN*64/256
constexpr int kBlkHid   = 12544;                // kEPad*128/256
constexpr int kBlkPrep  = 258;                  // 1032 slots * 64 lanes / 256
constexpr int kBlkDeg   = 98;                   // kEPad/256
constexpr int kB0H = kBlkDense;                 // 2500
constexpr int kB0P = kB0H + kBlkHid;            // 15044
constexpr int kB0G = kB0P + kBlkPrep;           // 15302
constexpr int kB0B = kB0G + kBlkDeg;            // 15400
constexpr int kBlkSetup = kB0B + 1;             // 15401

__global__ __launch_bounds__(256) void k_setup(
    const float* __restrict__ x, const float* __restrict__ W0, const float* __restrict__ b0,
    const float* __restrict__ ea, const float* __restrict__ We1, const float* __restrict__ be1,
    const float* __restrict__ We2, const float* __restrict__ be2,
    const int* __restrict__ ei, const int* __restrict__ batch,
    float* __restrict__ outn, unsigned short* __restrict__ hid2,
    unsigned short* __restrict__ Bc2, float* __restrict__ deg, int* __restrict__ start) {
  const int blk = blockIdx.x, t = threadIdx.x;
  if (blk < kB0H) {                   // ---- dense0: out = relu(x@W0+b0), [N,64]
    int gid = blk * 256 + t;
    int n = gid >> 6, f = gid & 63;
    float acc = b0[f];
    const float* xr = x + n * kNF;
#pragma unroll
    for (int j = 0; j < kNF; ++j) acc += xr[j] * W0[j * kD + f];
    outn[gid] = fmaxf(acc, 0.f);
  } else if (blk < kB0P) {            // ---- hidden: hid2[e][h] = bf16(relu(ea@We1+be1))
    int lg = (blk - kB0H) * 256 + t;
    int e = lg >> 7, h = lg & 127;
    float r = 0.f;
    if (e < kE) {
      float acc = be1[h];
      const float* er = ea + e * kEF;
#pragma unroll
      for (int j = 0; j < kEF; ++j) acc += er[j] * We1[j * 128 + h];
      r = fmaxf(acc, 0.f);
    }
    hid2[(size_t)e * 128 + h] = f2bf(r);
  } else if (blk < kB0G) {            // ---- prep B: fragment-major Bc2 for 32x32x16
    int lg = (blk - kB0P) * 256 + t;
    int lane = lg & 63, slot = lg >> 6;            // slot 0..1031
    int fcol, dbase;
    const float* srcmat;
    int h = 0;
    if (slot < 1024) {
      int wn_ = slot & 1, fidby = slot >> 1;
      int by = fidby >> 6, fid = fidby & 63;
      int db = fid & 3, hp = (fid >> 2) & 1, h2 = fid >> 3;
      h = by * 16 + h2 * 2 + hp;
      fcol = wn_ * 32 + (lane & 31);
      dbase = db * 16 + (lane >> 5) * 8;
      srcmat = We2 + (size_t)h * 4096;
    } else {
      int s = slot - 1024;
      int db = s >> 1, wn_ = s & 1;
      fcol = wn_ * 32 + (lane & 31);
      dbase = db * 16 + (lane >> 5) * 8;
      srcmat = be2;
    }
    unsigned short v[8];
#pragma unroll
    for (int j = 0; j < 8; ++j) v[j] = f2bf(srcmat[(size_t)(dbase + j) * 64 + fcol]);
    *(short8*)(Bc2 + (size_t)slot * 512 + lane * 8) = *(short8*)v;
  } else if (blk < kB0B) {            // ---- degree
    int e = (blk - kB0G) * 256 + t;
    if (e < kE) atomicAdd(&deg[ei[kE + e]], 1.f);
  } else {                            // ---- per-graph bounds (batch sorted)
    if (t > kB) return;
    int lo = 0, hi = kN;
    while (lo < hi) { int mid = (lo + hi) >> 1; if (batch[mid] < t) lo = mid + 1; else hi = mid; }
    start[t] = lo;
  }
}

// ============ fused message GEMM (32x32x16 MFMA, K-split by blockIdx.y) ============
// Block: 128 edges, K-chunk = 16 h values (K=1024). 4 waves = (wm: edge-half) x (wn: f-half).
// Wave: M=64 (2 sub-tiles of 32 edges), N=32, A = hid[e,h]*out[src(e),d] built in regs.
__global__ __launch_bounds__(256) void k_msg2(const int* __restrict__ ei,
    const float* __restrict__ outn, const unsigned short* __restrict__ hid2,
    const unsigned short* __restrict__ Bc2, float* __restrict__ agg) {
  __shared__ __align__(16) unsigned short hidL[128 * 16];   // [e_loc][16 h], 4 KB
  const int t = threadIdx.x, lane = t & 63, wave = t >> 6;
  const int wm = wave >> 1, wn = wave & 1;
  const int e0 = blockIdx.x * 128, by = blockIdx.y;
  {   // stage hid tile: per instr 32 edges x 16 h; linear LDS dest
    int eIdx = wave * 32 + (lane >> 1);
    const unsigned short* src = hid2 + (size_t)(e0 + eIdx) * 128 + by * 16 + (lane & 1) * 8;
    __builtin_amdgcn_global_load_lds(
        (const __attribute__((address_space(1))) void*)src,
        (__attribute__((address_space(3))) void*)((char*)hidL + wave * 1024 + lane * 16),
        16, 0, 0);
  }
  const int hi5 = lane >> 5, er = lane & 31;
  floatx4 o[2][4][2];        // [mf][db][pair]: d = db*16 + hi5*8 + {0..3, 4..7}
#pragma unroll
  for (int mf = 0; mf < 2; ++mf) {
    int e = e0 + wm * 64 + mf * 32 + er;
    int s = (e < kE) ? ei[e] : 0;
    const float* base = outn + (size_t)s * 64 + hi5 * 8;
#pragma unroll
    for (int db = 0; db < 4; ++db) {
      o[mf][db][0] = *(const floatx4*)(base + db * 16);
      o[mf][db][1] = *(const floatx4*)(base + db * 16 + 4);
    }
  }
  __syncthreads();
  floatx16 acc[2];
#pragma unroll
  for (int i = 0; i < 16; ++i) { acc[0][i] = 0.f; acc[1][i] = 0.f; }
  const int el0 = (wm * 64 + er) * 16;
  const int el1 = (wm * 64 + 32 + er) * 16;
#pragma unroll
  for (int h2 = 0; h2 < 8; ++h2) {
    unsigned hp0 = *(const unsigned*)&hidL[el0 + h2 * 2];
    unsigned hp1 = *(const unsigned*)&hidL[el1 + h2 * 2];
    float hv[2][2];
    hv[0][0] = __uint_as_float(hp0 << 16);
    hv[0][1] = __uint_as_float(hp0 & 0xffff0000u);
    hv[1][0] = __uint_as_float(hp1 << 16);
    hv[1][1] = __uint_as_float(hp1 & 0xffff0000u);
#pragma unroll
    for (int hp = 0; hp < 2; ++hp) {
#pragma unroll
      for (int db = 0; db < 4; ++db) {
        short8 bv = *(const short8*)(Bc2 +
            (size_t)(((by * 64 + (h2 * 2 + hp) * 4 + db) * 2 + wn) * 512 + lane * 8));
#pragma unroll
        for (int mf = 0; mf < 2; ++mf) {
          float h = hv[mf][hp];
          floatx4 va = o[mf][db][0] * h;       // hoping for v_pk_mul_f32
          floatx4 vb = o[mf][db][1] * h;
          union { uint4 u; short8 s; } U;
          U.u.x = cvtpk(va.x, va.y);
          U.u.y = cvtpk(va.z, va.w);
          U.u.z = cvtpk(vb.x, vb.y);
          U.u.w = cvtpk(vb.z, vb.w);
          acc[mf] = __builtin_amdgcn_mfma_f32_32x32x16_bf16(U.s, bv, acc[mf], 0, 0, 0);
        }
      }
    }
  }
  if (by == 7) {    // bias chunk: msg += out @ reshape(be2, 64,64)
#pragma unroll
    for (int db = 0; db < 4; ++db) {
      short8 bv = *(const short8*)(Bc2 + (size_t)((1024 + db * 2 + wn) * 512 + lane * 8));
#pragma unroll
      for (int mf = 0; mf < 2; ++mf) {
        floatx4 va = o[mf][db][0], vb = o[mf][db][1];
        union { uint4 u; short8 s; } U;
        U.u.x = cvtpk(va.x, va.y);
        U.u.y = cvtpk(va.z, va.w);
        U.u.z = cvtpk(vb.x, vb.y);
        U.u.w = cvtpk(vb.z, vb.w);
        acc[mf] = __builtin_amdgcn_mfma_f32_32x32x16_bf16(U.s, bv, acc[mf], 0, 0, 0);
      }
    }
  }
  // epilogue: D layout col=lane&31, row=(reg&3)+8*(reg>>2)+4*(lane>>5)
#pragma unroll
  for (int mf = 0; mf < 2; ++mf) {
#pragma unroll
    for (int reg = 0; reg < 16; ++reg) {
      int row = (reg & 3) + 8 * (reg >> 2) + 4 * hi5;
      int e = e0 + wm * 64 + mf * 32 + row;
      if (e < kE) {
        int dst = ei[kE + e];
        atomicAdd(agg + (size_t)dst * 64 + wn * 32 + er, acc[mf][reg]);
      }
    }
  }
}

// ============ fused NNConv-combine + GRU cell (16 nodes/block); self-zeros agg ============
__global__ __launch_bounds__(256) void k_update(const float* __restrict__ agg_in,
    const float* __restrict__ deg, const float* __restrict__ root,
    const float* __restrict__ convb, const float* __restrict__ Wi,
    const float* __restrict__ bi, const float* __restrict__ Wh,
    const float* __restrict__ bh, float* __restrict__ out, float* __restrict__ agg_clr) {
  __shared__ float sh_out[16][64];
  __shared__ float sh_m[16][64];
  int t = threadIdx.x, lane = t & 63, w = t >> 6;
  int nb = blockIdx.x * 16;
#pragma unroll
  for (int i = 0; i < 4; ++i) {
    int idx = t + i * 256;
    sh_out[idx >> 6][idx & 63] = out[(size_t)(nb + (idx >> 6)) * 64 + (idx & 63)];
  }
  __syncthreads();
  int n0 = w * 4;
  float acc[4];
#pragma unroll
  for (int i = 0; i < 4; ++i) {
    int n = nb + n0 + i;
    float dg = fmaxf(deg[n], 1.f);
    acc[i] = agg_in[(size_t)n * 64 + lane] / dg + convb[lane];
    agg_clr[(size_t)n * 64 + lane] = 0.f;        // ready for next iteration / next call
  }
  for (int d = 0; d < 64; ++d) {
    float rv = root[d * 64 + lane];
#pragma unroll
    for (int i = 0; i < 4; ++i) acc[i] += sh_out[n0 + i][d] * rv;
  }
#pragma unroll
  for (int i = 0; i < 4; ++i) sh_m[n0 + i][lane] = fmaxf(acc[i], 0.f);
  __syncthreads();
  float ir[4] = {}, iz[4] = {}, ig[4] = {}, hr[4] = {}, hz[4] = {}, hg[4] = {};
  for (int d = 0; d < 64; ++d) {
    float wi0 = Wi[d * 192 + lane], wi1 = Wi[d * 192 + 64 + lane], wi2 = Wi[d * 192 + 128 + lane];
    float wh0 = Wh[d * 192 + lane], wh1 = Wh[d * 192 + 64 + lane], wh2 = Wh[d * 192 + 128 + lane];
#pragma unroll
    for (int i = 0; i < 4; ++i) {
      float mv = sh_m[n0 + i][d], hv = sh_out[n0 + i][d];
      ir[i] += mv * wi0; iz[i] += mv * wi1; ig[i] += mv * wi2;
      hr[i] += hv * wh0; hz[i] += hv * wh1; hg[i] += hv * wh2;
    }
  }
  float bi0 = bi[lane], bi1 = bi[64 + lane], bi2 = bi[128 + lane];
  float bh0 = bh[lane], bh1 = bh[64 + lane], bh2 = bh[128 + lane];
#pragma unroll
  for (int i = 0; i < 4; ++i) {
    float r = sigmf(ir[i] + bi0 + hr[i] + bh0);
    float z = sigmf(iz[i] + bi1 + hz[i] + bh1);
    float nn = tanh_(ig[i] + bi2 + r * (hg[i] + bh2));
    float h = sh_out[n0 + i][lane];
    out[(size_t)(nb + n0 + i) * 64 + lane] = (1.f - z) * nn + z * h;
  }
}

// ============ all 3 Set2Set steps + head1 in one kernel (block = graph) ============
__global__ __launch_bounds__(256) void k_s2s3(const float* __restrict__ out,
    const int* __restrict__ start, const float* __restrict__ Wli,
    const float* __restrict__ bli, const float* __restrict__ Wlh,
    const float* __restrict__ blh, const float* __restrict__ Wr1,
    const float* __restrict__ br1, float* __restrict__ y1) {
  __shared__ float qs[128], hls[64], cls[64], gates[256];
  __shared__ float ebuf[1024];
  __shared__ float part[4][64];
  __shared__ float sred[8];
  int b = blockIdx.x, t = threadIdx.x, lane = t & 63, w = t >> 6;
  if (t < 128) qs[t] = 0.f;
  if (t < 64) { hls[t] = 0.f; cls[t] = 0.f; }
  int s0 = start[b], s1 = start[b + 1];
  int cnt = s1 - s0; if (cnt > 1024) cnt = 1024;
  __syncthreads();
  for (int it = 0; it < 3; ++it) {
    float g = bli[t] + blh[t];
    for (int j = 0; j < 128; ++j) g += qs[j] * Wli[j * 256 + t];
    for (int j = 0; j < 64; ++j) g += hls[j] * Wlh[j * 256 + t];
    gates[t] = g;
    __syncthreads();
    if (t < 64) {                      // gate order i, f, g, o
      float ig = sigmf(gates[t]), fg = sigmf(gates[64 + t]);
      float gg = tanh_(gates[128 + t]), og = sigmf(gates[192 + t]);
      float c = fg * cls[t] + ig * gg;
      float h = og * tanh_(c);
      cls[t] = c; hls[t] = h;
      qs[t] = h;                       // q part of q_star
    }
    __syncthreads();
    for (int idx = w; idx < cnt; idx += 4) {           // e[n] = <out[n], q>
      int node = s0 + idx;
      float p = out[(size_t)node * 64 + lane] * hls[lane];
#pragma unroll
      for (int m = 1; m < 64; m <<= 1) p += __shfl_xor(p, m, 64);
      if (lane == 0) ebuf[idx] = p;
    }
    __syncthreads();
    float mx = -3.4e38f;
    for (int idx = t; idx < cnt; idx += 256) mx = fmaxf(mx, ebuf[idx]);
#pragma unroll
    for (int m = 1; m < 64; m <<= 1) mx = fmaxf(mx, __shfl_xor(mx, m, 64));
    if (lane == 0) sred[w] = mx;
    __syncthreads();
    mx = fmaxf(fmaxf(sred[0], sred[1]), fmaxf(sred[2], sred[3]));
    float s = 0.f;
    for (int idx = t; idx < cnt; idx += 256) {
      float a = __expf(ebuf[idx] - mx);
      ebuf[idx] = a; s += a;
    }
#pragma unroll
    for (int m = 1; m < 64; m <<= 1) s += __shfl_xor(s, m, 64);
    if (lane == 0) sred[4 + w] = s;
    __syncthreads();
    s = sred[4] + sred[5] + sred[6] + sred[7];
    float rs = 1.f / fmaxf(s, 1e-12f);
    float pr = 0.f;
    for (int idx = w; idx < cnt; idx += 4) {
      int node = s0 + idx;
      pr += ebuf[idx] * out[(size_t)node * 64 + lane];
    }
    part[w][lane] = pr;
    __syncthreads();
    if (t < 64)
      qs[64 + t] = (part[0][t] + part[1][t] + part[2][t] + part[3][t]) * rs;
    __syncthreads();
  }
  if (t < 64) {                        // head1: y1 = q_star @ Wr1 + br1
    float acc = br1[t];
    for (int j = 0; j < 128; ++j) acc += qs[j] * Wr1[j * 64 + t];
    y1[b * 64 + t] = acc;
  }
}

// ============ head2: BatchNorm (batch stats) + relu + Wr2 ============
__global__ __launch_bounds__(256) void k_head2(const float* __restrict__ y1,
    const float* __restrict__ gamma, const float* __restrict__ beta,
    const float* __restrict__ Wr2, const float* __restrict__ br2,
    float* __restrict__ outp) {
  __shared__ float mu[64], ri[64];
  int t = threadIdx.x;
  if (t < 64) {
    float s1 = 0.f, s2 = 0.f;
    for (int b = 0; b < kB; ++b) { float v = y1[b * 64 + t]; s1 += v; s2 += v * v; }
    float m = s1 / (float)kB;
    mu[t] = m; ri[t] = rsqrtf(s2 / (float)kB - m * m + 1e-5f);
  }
  __syncthreads();
  if (t < kB) {
    float acc = br2[0];
    for (int f = 0; f < 64; ++f) {
      float v = (y1[t * 64 + f] - mu[f]) * ri[f] * gamma[f] + beta[f];
      acc += fmaxf(v, 0.f) * Wr2[f];
    }
    outp[t] = acc;
  }
}

extern "C" void kernel_launch(void* const* d_in, const int* in_sizes, int n_in,
                              void* d_out, int out_size, void* d_ws, size_t ws_size,
                              hipStream_t stream) {
  const float* x     = (const float*)d_in[0];
  const int*   ei    = (const int*)d_in[1];
  const float* ea    = (const float*)d_in[2];
  const int*   batch = (const int*)d_in[3];
  const float* W0    = (const float*)d_in[4];
  const float* b0    = (const float*)d_in[5];
  const float* We1   = (const float*)d_in[6];
  const float* be1   = (const float*)d_in[7];
  const float* We2   = (const float*)d_in[8];
  const float* be2   = (const float*)d_in[9];
  const float* root  = (const float*)d_in[10];
  const float* convb = (const float*)d_in[11];
  const float* Wi    = (const float*)d_in[12];
  const float* bi    = (const float*)d_in[13];
  const float* Wh    = (const float*)d_in[14];
  const float* bh    = (const float*)d_in[15];
  const float* Wli   = (const float*)d_in[16];
  const float* bli   = (const float*)d_in[17];
  const float* Wlh   = (const float*)d_in[18];
  const float* blh   = (const float*)d_in[19];
  const float* Wr1   = (const float*)d_in[20];
  const float* br1   = (const float*)d_in[21];
  const float* gamma = (const float*)d_in[22];
  const float* beta  = (const float*)d_in[23];
  const float* Wr2   = (const float*)d_in[24];
  const float* br2   = (const float*)d_in[25];
  (void)in_sizes; (void)n_in; (void)out_size; (void)ws_size;

  char* ws = (char*)d_ws;
  size_t off = 0;
  auto take = [&](size_t bytes) {
    char* p = ws + off;
    off += (bytes + 255) & ~(size_t)255;
    return p;
  };
  // zero-region (one memset covers deg..agg, contiguous)
  float* deg  = (float*)take((size_t)kN * 4);                 // 40192 padded
  float* agg  = (float*)take((size_t)kN * kD * 4);            // 2.56 MB
  size_t zeroBytes = off;
  int*   start = (int*)take(256 * 4);
  float* outn  = (float*)take((size_t)kN * kD * 4);
  unsigned short* hid2 = (unsigned short*)take((size_t)kEPad * 128 * 2);  // 6.4 MB
  unsigned short* Bc2  = (unsigned short*)take((size_t)1032 * 512 * 2);   // 1.03 MB
  float* y1    = (float*)take((size_t)kB * 64 * 4);

  hipMemsetAsync(deg, 0, zeroBytes, stream);
  k_setup<<<kBlkSetup, 256, 0, stream>>>(x, W0, b0, ea, We1, be1, We2, be2, ei, batch,
                                         outn, hid2, Bc2, deg, start);
  dim3 gm(kEPad / 128, 8);
  for (int s = 0; s < 3; ++s) {
    k_msg2<<<gm, 256, 0, stream>>>(ei, outn, hid2, Bc2, agg);
    k_update<<<kN / 16, 256, 0, stream>>>(agg, deg, root, convb, Wi, bi, Wh, bh, outn, agg);
  }
  k_s2s3<<<kB, 256, 0, stream>>>(outn, start, Wli, bli, Wlh, blh, Wr1, br1, y1);
  k_head2<<<1, 256, 0, stream>>>(y1, gamma, beta, Wr2, br2, (float*)d_out);
}